// Round 13
// baseline (233.139 us; speedup 1.0000x reference)
//
#include <hip/hip_runtime.h>

typedef short bf16x8 __attribute__((ext_vector_type(8)));
typedef float f32x4 __attribute__((ext_vector_type(4)));
typedef float f32x16 __attribute__((ext_vector_type(16)));
typedef unsigned short u16x8 __attribute__((ext_vector_type(8)));

#define DEVI __device__ __forceinline__

// Problem constants: B=4, T=2048, D=1024, H=16, DH=64
static constexpr int T_ = 2048;

DEVI unsigned short f2bf(float f) {
  unsigned int x = __builtin_bit_cast(unsigned int, f);
  x += 0x7fffu + ((x >> 16) & 1u);     // RNE
  return (unsigned short)(x >> 16);
}

DEVI unsigned int cvtpk(float lo, float hi2) {  // low16=bf16(lo), high16=bf16(hi2), RNE
  unsigned int r;
  asm("v_cvt_pk_bf16_f32 %0, %1, %2" : "=v"(r) : "v"(lo), "v"(hi2));
  return r;
}

DEVI float exp2_raw(float x) {  // raw v_exp_f32 (2^x); x <= 0 here
  float r;
  asm("v_exp_f32 %0, %1" : "=v"(r) : "v"(x));
  return r;
}

DEVI int swz23(int r) {  // swap bits 2 and 3 (involution)
  const int d = ((r >> 2) ^ (r >> 3)) & 1;
  return r ^ (d << 2) ^ (d << 3);
}

DEVI bf16x8 mkfrag(unsigned a, unsigned b, unsigned c, unsigned d) {
  union { unsigned u[4]; bf16x8 v; } x;
  x.u[0] = a; x.u[1] = b; x.u[2] = c; x.u[3] = d;
  return x.v;
}

DEVI void gl2lds16(const void* g, const void* l) {
  __builtin_amdgcn_global_load_lds(
      (const __attribute__((address_space(1))) void*)g,
      (__attribute__((address_space(3))) void*)l, 16, 0, 0);
}

// ---------------------------------------------------------------- cast f32->bf16
__global__ __launch_bounds__(256) void k_cvt_bf16(const float* __restrict__ in,
                                                  unsigned short* __restrict__ out) {
  size_t i = ((size_t)blockIdx.x * 256 + threadIdx.x) * 8;
  float4 a = *(const float4*)(in + i);
  float4 b = *(const float4*)(in + i + 4);
  u16x8 o;
  o[0] = f2bf(a.x); o[1] = f2bf(a.y); o[2] = f2bf(a.z); o[3] = f2bf(a.w);
  o[4] = f2bf(b.x); o[5] = f2bf(b.y); o[6] = f2bf(b.z); o[7] = f2bf(b.w);
  *(u16x8*)(out + i) = o;
}

// ---------------------------------------------------------------- mask all-ones scan
__global__ __launch_bounds__(256) void k_mask_scan(const uint4* __restrict__ m,
                                                   unsigned int* __restrict__ flag) {
  const unsigned int ONE = 0x3f800000u;
  size_t i0 = ((size_t)blockIdx.x * 256 + threadIdx.x) * 8;   // 8 uint4 per thread
  bool ok = true;
#pragma unroll
  for (int i = 0; i < 8; ++i) {
    uint4 v = m[i0 + i];
    ok &= (v.x == ONE) & (v.y == ONE) & (v.z == ONE) & (v.w == ONE);
  }
  if (!ok) atomicAnd(flag, 0u);
}

// ------------------------------------------- transpose + cast: in f32[R][C] -> out bf16[C][R]
template <int R, int C>
__global__ __launch_bounds__(256) void k_transpose_cvt(const float* __restrict__ in,
                                                       unsigned short* __restrict__ out) {
  __shared__ unsigned short t[64][65];
  const int c0 = blockIdx.x * 64, r0 = blockIdx.y * 64;
  const int cc = threadIdx.x & 63, r4 = threadIdx.x >> 6;
#pragma unroll
  for (int i = 0; i < 16; ++i) {
    int rr = i * 4 + r4;
    t[rr][cc] = f2bf(in[(size_t)(r0 + rr) * C + c0 + cc]);
  }
  __syncthreads();
#pragma unroll
  for (int i = 0; i < 16; ++i) {
    int rr = i * 4 + r4;                       // output row (a column of in)
    out[(size_t)(c0 + rr) * R + r0 + cc] = t[cc][rr];
  }
}

// ---------------------------------------------- V[b,h,t,d] -> Vt[b,h,d,t]  (bf16)
__global__ __launch_bounds__(256) void k_transpose_v(const unsigned short* __restrict__ V,
                                                     unsigned short* __restrict__ Vt) {
  __shared__ unsigned short t[64][65];
  const int t0 = blockIdx.x * 64;
  const size_t bh = blockIdx.y;
  const unsigned short* src = V + (bh * T_ + t0) * 64;
  unsigned short* dst = Vt + bh * 64 * T_ + t0;
  const int cc = threadIdx.x & 63, r4 = threadIdx.x >> 6;
#pragma unroll
  for (int i = 0; i < 16; ++i) {
    int rr = i * 4 + r4;                       // t-local
    t[rr][cc] = src[(size_t)rr * 64 + cc];
  }
  __syncthreads();
#pragma unroll
  for (int i = 0; i < 16; ++i) {
    int rr = i * 4 + r4;                       // d
    dst[(size_t)rr * T_ + cc] = t[cc][rr];
  }
}

// ---------------------------------------------------------------- GEMM 256x128, BK=64
// round-10 ring structure (3-deep LDS ring + counted vmcnt), NEW: 32x32x16 MFMA
// (half the MFMA instructions, faster shape; A/B/C layouts validated by k_attn).
// 512 thr = 8 waves (4M x 2N), per-wave 64x64 out. grid % 8 == 0, XCD-swizzled.
template <int EPI, int NT>   // NT = N/128
__global__ __launch_bounds__(512, 2) void k_gemm8(
    const unsigned short* __restrict__ A, const unsigned short* __restrict__ Bt,
    const float* __restrict__ bias,
    unsigned short* __restrict__ qo, unsigned short* __restrict__ ko2,
    unsigned short* __restrict__ vo, float* __restrict__ fo) {
  __shared__ unsigned short As[3][256 * 64];   // 96 KiB
  __shared__ unsigned short Bs[3][128 * 64];   // 48 KiB
  const int tid = threadIdx.x, lane = tid & 63, w = tid >> 6;
  const int wm = w >> 1, wn = w & 1;           // 4 x 2 waves
  const int q32 = lane & 31, hi = lane >> 5;

  const int flat = blockIdx.x;                 // nwg = 32*NT, % 8 == 0
  const int work = (flat & 7) * ((32 * NT) >> 3) + (flat >> 3);
  const int m0 = (work / NT) * 256, n0 = (work % NT) * 128;

  f32x16 acc[2][2] = {};                       // 32x32 fragments, 2x2 per wave

  // staging: slot s = tid + j*512 -> row s>>3, LDS chunk s&7 holds global chunk (s&7)^(row&7)
  const int rs = tid >> 3, chs = tid & 7;
  const int lwb = w * 512;                     // wave base (ushort) within a j-section

  auto stageK = [&](int buf, int kt) {
    const unsigned short* sa = A + (size_t)m0 * 1024 + kt * 64;
    const unsigned short* sb = Bt + (size_t)n0 * 1024 + kt * 64;
    unsigned short* da = &As[buf][0];
    unsigned short* db = &Bs[buf][0];
#pragma unroll
    for (int j = 0; j < 4; ++j) {
      const int row = rs + j * 64;
      const int ch = chs ^ (row & 7);
      gl2lds16(sa + (size_t)row * 1024 + ch * 8, da + j * 4096 + lwb);
    }
#pragma unroll
    for (int j = 0; j < 2; ++j) {
      const int row = rs + j * 64;
      const int ch = chs ^ (row & 7);
      gl2lds16(sb + (size_t)row * 1024 + ch * 8, db + j * 4096 + lwb);
    }
  };

  // prologue: contents 0,1 (12 loads); vmcnt(6) -> content 0 landed
  stageK(0, 0);
  stageK(1, 1);
  asm volatile("s_waitcnt vmcnt(6)" ::: "memory");
  __builtin_amdgcn_s_barrier();

  int cb = 0;
  for (int k = 0; k < 16; ++k) {
    // fragments: A row = m-local (lane&31), k = ks*16 + hi*8 + j  (chunk ks*2+hi)
    bf16x8 af[2][4], bfv[2][4];
#pragma unroll
    for (int mf = 0; mf < 2; ++mf) {
      const int row = wm * 64 + mf * 32 + q32;
#pragma unroll
      for (int ks = 0; ks < 4; ++ks) {
        const int ch = (ks * 2 + hi) ^ (row & 7);
        af[mf][ks] = *(const bf16x8*)&As[cb][row * 64 + ch * 8];
      }
    }
#pragma unroll
    for (int nf = 0; nf < 2; ++nf) {
      const int row = wn * 64 + nf * 32 + q32;
#pragma unroll
      for (int ks = 0; ks < 4; ++ks) {
        const int ch = (ks * 2 + hi) ^ (row & 7);
        bfv[nf][ks] = *(const bf16x8*)&Bs[cb][row * 64 + ch * 8];
      }
    }
    if (k + 2 < 16) stageK((cb + 2) % 3, k + 2);
    __builtin_amdgcn_s_barrier();
    asm volatile("s_waitcnt lgkmcnt(0)" ::: "memory");
    __builtin_amdgcn_sched_barrier(0);
#pragma unroll
    for (int ks = 0; ks < 4; ++ks)
#pragma unroll
      for (int mf = 0; mf < 2; ++mf)
#pragma unroll
        for (int nf = 0; nf < 2; ++nf)
          acc[mf][nf] = __builtin_amdgcn_mfma_f32_32x32x16_bf16(af[mf][ks], bfv[nf][ks], acc[mf][nf], 0, 0, 0);
    if (k <= 13)      asm volatile("s_waitcnt vmcnt(6)" ::: "memory");
    else if (k == 14) asm volatile("s_waitcnt vmcnt(0)" ::: "memory");
    __builtin_amdgcn_s_barrier();
    cb = (cb == 2) ? 0 : cb + 1;
  }

  // epilogue: C 32x32 layout: col = lane&31, row = (r&3) + 8*(r>>2) + 4*hi
#pragma unroll
  for (int mf = 0; mf < 2; ++mf) {
#pragma unroll
    for (int nf = 0; nf < 2; ++nf) {
      const int n = n0 + wn * 64 + nf * 32 + q32;
      const float bv = bias[n];
#pragma unroll
      for (int r = 0; r < 16; ++r) {
        const int m = m0 + wm * 64 + mf * 32 + (r & 3) + 8 * (r >> 2) + 4 * hi;
        float v = acc[mf][nf][r] + bv;
        if constexpr (EPI == 0) {
          const int sel = n >> 10, hd = n & 1023;
          const int h = hd >> 6, d = hd & 63;
          const int b = m >> 11, t = m & 2047;
          const size_t off = ((size_t)((b * 16 + h) * 2048 + t)) * 64 + d;
          if (sel == 0)       qo[off] = f2bf(v * 0.125f);   // q * DH^-0.5
          else if (sel == 1)  ko2[off] = f2bf(v);
          else                vo[off] = f2bf(v);
        } else {
          fo[(size_t)m * 1024 + n] = v;
        }
      }
    }
  }
}

// ---------------------------------------------------------------- flash attention
// (round-8/10 version -- best measured: 99.2-99.6 us across three runs)
// Swapped-operand: S^T = mfma(K,Q), lane owns q-row (q=lane&31); in-register softmax.
// K rows stored at LDS row swz23(t): lane's P register pairs map DIRECTLY onto
// PV B-fragment dwords (no cross-lane pack). PV as O^T = mfma(Vt,P).
// 4 waves x 32 q = 128 q / block; grid 1024 (XCD-swizzled); KVBLK=64 dbuf.
__global__ __launch_bounds__(256, 4) void k_attn(
    const unsigned short* __restrict__ Q, const unsigned short* __restrict__ Kg_,
    const unsigned short* __restrict__ Vt, const float* __restrict__ mask,
    const unsigned int* __restrict__ maskflag,
    unsigned short* __restrict__ ctx) {
  __shared__ unsigned short Ks[2][64 * 64];
  __shared__ unsigned short Vs[2][64 * 64];
  const int tid = threadIdx.x, lane = tid & 63, w = tid >> 6;
  const int q = lane & 31, hi = lane >> 5;

  // bijective XCD swizzle (1024 % 8 == 0): colocate the 16 q-blocks of one bh
  const int flat = blockIdx.x + 16 * blockIdx.y + 256 * blockIdx.z;
  const int work = (flat & 7) * 128 + (flat >> 3);
  const int qb = work & 15;
  const int bh_i = work >> 4;            // b*16 + h
  const int h = bh_i & 15, b = bh_i >> 4;
  const int t0 = qb * 128;
  const size_t bh = (size_t)bh_i;

  const unsigned short* Qg = Q + (bh * 2048 + t0 + w * 32 + q) * 64;
  const unsigned short* Kg = Kg_ + bh * 2048 * 64;
  const unsigned short* Vg = Vt + bh * 64 * 2048;
  const float* Mg = mask + (size_t)b * 2048 * 2048;
  const bool allones = (*maskflag != 0u);

  // Q as B-fragment of mfma(K,Q): lane: n=q, k = kd*16 + hi*8 + j
  bf16x8 qf[4];
#pragma unroll
  for (int kd = 0; kd < 4; ++kd)
    qf[kd] = *(const bf16x8*)(Qg + kd * 16 + hi * 8);

  f32x16 ot[2] = {};        // O^T acc: col=q, row d = dt*32 + (reg&3)+8*(reg>>2)+4*hi
  float mrun = -__builtin_inff(), lrun = 0.f;

  // staging: 128B rows, 8 chunks; LDS[r][ch] holds global chunk ch ^ (r&7).
  // K additionally row-permuted: LDS row r holds global K row swz23(r).
  const int s0 = tid, s1 = tid + 256;
  const int kr0 = s0 >> 3, kc0 = (s0 & 7) ^ (kr0 & 7);
  const int kr1 = s1 >> 3, kc1 = (s1 & 7) ^ (kr1 & 7);
  const int kp0 = swz23(kr0), kp1 = swz23(kr1);
  const int ldsb0 = w * 512, ldsb1 = w * 512 + 2048;

  auto stageKV = [&](int buf, int kt) {
    gl2lds16(Kg + (size_t)(kt * 64 + kp0) * 64 + kc0 * 8, &Ks[buf][ldsb0]);
    gl2lds16(Kg + (size_t)(kt * 64 + kp1) * 64 + kc1 * 8, &Ks[buf][ldsb1]);
    gl2lds16(Vg + (size_t)kr0 * 2048 + kt * 64 + kc0 * 8, &Vs[buf][ldsb0]);
    gl2lds16(Vg + (size_t)kr1 * 2048 + kt * 64 + kc1 * 8, &Vs[buf][ldsb1]);
  };

  stageKV(0, 0);
  __syncthreads();
  int cur = 0;
  const float MINF = -3.402823466e38f;
  const float L2E = 1.4426950408889634f;

  for (int kt = 0; kt < 32; ++kt) {
    if (kt + 1 < 32) stageKV(cur ^ 1, kt + 1);

    // S^T[m][q]: A = K rows from LDS (m = LDS row; global t2 = swz23(m)), B = Q frags
    f32x16 st[2] = {};
#pragma unroll
    for (int mt2 = 0; mt2 < 2; ++mt2) {
      __builtin_amdgcn_s_setprio(1);
#pragma unroll
      for (int kd = 0; kd < 4; ++kd) {
        const int row = mt2 * 32 + q;
        const int ch = (2 * kd + hi) ^ (row & 7);
        bf16x8 kf = *(const bf16x8*)&Ks[cur][row * 64 + ch * 8];
        st[mt2] = __builtin_amdgcn_mfma_f32_32x32x16_bf16(kf, qf[kd], st[mt2], 0, 0, 0);
      }
      __builtin_amdgcn_s_setprio(0);
    }

    // mask fallback: reg r holds m = (r&3)+4*hi+8*(r>>2); t2 = swz23(m)
    if (!allones) {
      const int qg = t0 + w * 32 + q;
#pragma unroll
      for (int mt2 = 0; mt2 < 2; ++mt2)
#pragma unroll
        for (int r = 0; r < 16; ++r) {
          const int kg = kt * 64 + mt2 * 32 +
                         (r & 3) + 4 * ((r >> 2) & 1) + 8 * hi + 16 * (r >> 3);
          const float mv = Mg[(size_t)qg * 2048 + kg];
          st[mt2][r] = st[mt2][r] * mv + (1.f - mv) * MINF;
        }
    }

    // ---- in-register online softmax ----
    float g4[8];
#pragma unroll
    for (int i = 0; i < 4; ++i) {
      g4[i]     = fmaxf(fmaxf(fmaxf(st[0][4 * i], st[0][4 * i + 1]), st[0][4 * i + 2]), st[0][4 * i + 3]);
      g4[i + 4] = fmaxf(fmaxf(fmaxf(st[1][4 * i], st[1][4 * i + 1]), st[1][4 * i + 2]), st[1][4 * i + 3]);
    }
    float r1 = fmaxf(fmaxf(g4[0], g4[1]), g4[2]);
    float r2 = fmaxf(fmaxf(g4[3], g4[4]), g4[5]);
    float r3 = fmaxf(fmaxf(g4[6], g4[7]), r1);
    float tmax = fmaxf(r2, r3);
    tmax = fmaxf(tmax, __shfl_xor(tmax, 32));
    const bool defer = (__all(tmax <= mrun + 8.f) != 0);   // T13 defer-max, THR=8
    float alpha = 1.f;
    if (!defer) {
      const float mnew = fmaxf(mrun, tmax);
      alpha = exp2_raw((mrun - mnew) * L2E);   // first iter: exp2(-inf)=0
      mrun = mnew;
    }
    const float mL2 = mrun * L2E;
#pragma unroll
    for (int mt2 = 0; mt2 < 2; ++mt2)
#pragma unroll
      for (int i = 0; i < 16; ++i)
        st[mt2][i] = exp2_raw(st[mt2][i] * L2E - mL2);
    float s8[8];
#pragma unroll
    for (int i = 0; i < 8; ++i)
      s8[i] = (st[0][i] + st[0][i + 8]) + (st[1][i] + st[1][i + 8]);
    float s4a = s8[0] + s8[4], s4b = s8[1] + s8[5];
    float s4c = s8[2] + s8[6], s4d = s8[3] + s8[7];
    float ps = (s4a + s4b) + (s4c + s4d);
    ps += __shfl_xor(ps, 32);
    lrun = lrun * alpha + ps;
    if (!defer) {
#pragma unroll
      for (int dt = 0; dt < 2; ++dt)
#pragma unroll
        for (int i = 0; i < 16; ++i) ot[dt][i] *= alpha;
    }

    // pack P to bf16 fragments -- pure in-lane thanks to the swz23 K-row layout
    bf16x8 pf[4];
#pragma unroll
    for (int mt2 = 0; mt2 < 2; ++mt2) {
      unsigned int pw[8];
#pragma unroll
      for (int i = 0; i < 8; ++i) pw[i] = cvtpk(st[mt2][2 * i], st[mt2][2 * i + 1]);
      pf[2 * mt2]     = mkfrag(pw[0], pw[1], pw[2], pw[3]);
      pf[2 * mt2 + 1] = mkfrag(pw[4], pw[5], pw[6], pw[7]);
    }

    // O^T += V^T P^T
#pragma unroll
    for (int dt = 0; dt < 2; ++dt) {
      __builtin_amdgcn_s_setprio(1);
#pragma unroll
      for (int kt2 = 0; kt2 < 4; ++kt2) {
        const int row = dt * 32 + q;
        const int ch = (2 * kt2 + hi) ^ (row & 7);
        bf16x8 vf = *(const bf16x8*)&Vs[cur][row * 64 + ch * 8];
        ot[dt] = __builtin_amdgcn_mfma_f32_32x32x16_bf16(vf, pf[kt2], ot[dt], 0, 0, 0);
      }
      __builtin_amdgcn_s_setprio(0);
    }

    __syncthreads();
    cur ^= 1;
  }

  // epilogue: lane owns q-row; d = dt*32 + rg*8 + hi*4 + {0..3} contiguous
  const int qg = t0 + w * 32 + q;
  const float rl = 1.f / lrun;
  unsigned short* cp = ctx + ((size_t)b * 2048 + qg) * 1024 + h * 64;
#pragma unroll
  for (int dt = 0; dt < 2; ++dt) {
#pragma unroll
    for (int rg = 0; rg < 4; ++rg) {
      const int d0 = dt * 32 + rg * 8 + hi * 4;
      ushort4 o;
      o.x = f2bf(ot[dt][rg * 4 + 0] * rl);
      o.y = f2bf(ot[dt][rg * 4 + 1] * rl);
      o.z = f2bf(ot[dt][rg * 4 + 2] * rl);
      o.w = f2bf(ot[dt][rg * 4 + 3] * rl);
      *(ushort4*)(cp + d0) = o;
    }
  }
}

// ----------------------------------------------------------------------------
extern "C" void kernel_launch(void* const* d_in, const int* in_sizes, int n_in,
                              void* d_out, int out_size, void* d_ws, size_t ws_size,
                              hipStream_t stream) {
  (void)in_sizes; (void)n_in; (void)out_size; (void)ws_size;
  const float* x    = (const float*)d_in[0];
  const float* Wqkv = (const float*)d_in[1];
  const float* bqkv = (const float*)d_in[2];
  const float* Wout = (const float*)d_in[3];
  const float* bout = (const float*)d_in[4];
  const float* mask = (const float*)d_in[5];
  float* out = (float*)d_out;
  char* ws = (char*)d_ws;

  const size_t SZ_BTD = (size_t)8192 * 1024 * 2;  // 16 MiB bf16 [B*T, D]
  unsigned short* xb  = (unsigned short*)(ws);
  unsigned short* Wqt = (unsigned short*)(ws + SZ_BTD);
  unsigned short* Wot = (unsigned short*)(ws + SZ_BTD + 6291456);
  unsigned short* Qb  = (unsigned short*)(ws + SZ_BTD + 8388608);
  unsigned short* Kb  = (unsigned short*)(ws + SZ_BTD + 8388608 + SZ_BTD);
  unsigned short* Vb  = (unsigned short*)(ws + SZ_BTD + 8388608 + 2 * SZ_BTD);
  unsigned short* Vtb = (unsigned short*)(ws + SZ_BTD + 8388608 + 3 * SZ_BTD);
  unsigned int* flag  = (unsigned int*)(ws + SZ_BTD + 8388608 + 4 * SZ_BTD);
  unsigned short* ctx = xb;  // reuse x_bf16 region (dead after gemm1)

  hipMemsetAsync(flag, 1, 4, stream);   // nonzero = "all ones so far"
  k_mask_scan<<<2048, 256, 0, stream>>>((const uint4*)mask, flag);
  k_cvt_bf16<<<4096, 256, 0, stream>>>(x, xb);
  k_transpose_cvt<1024, 3072><<<dim3(48, 16), 256, 0, stream>>>(Wqkv, Wqt);
  k_transpose_cvt<1024, 1024><<<dim3(16, 16), 256, 0, stream>>>(Wout, Wot);
  k_gemm8<0, 24><<<768, 512, 0, stream>>>(xb, Wqt, bqkv, Qb, Kb, Vb, nullptr);
  k_transpose_v<<<dim3(32, 64), 256, 0, stream>>>(Vb, Vtb);
  k_attn<<<dim3(16, 16, 4), 256, 0, stream>>>(Qb, Kb, Vtb, mask, flag, ctx);
  k_gemm8<1, 8><<<256, 512, 0, stream>>>(ctx, Wot, bout, nullptr, nullptr, nullptr, out);
}

// Round 14
// 224.028 us; speedup vs baseline: 1.0407x; 1.0407x over previous
//
#include <hip/hip_runtime.h>

typedef short bf16x8 __attribute__((ext_vector_type(8)));
typedef float f32x4 __attribute__((ext_vector_type(4)));
typedef float f32x16 __attribute__((ext_vector_type(16)));
typedef unsigned short u16x8 __attribute__((ext_vector_type(8)));

#define DEVI __device__ __forceinline__

// Problem constants: B=4, T=2048, D=1024, H=16, DH=64
static constexpr int T_ = 2048;

DEVI unsigned short f2bf(float f) {
  unsigned int x = __builtin_bit_cast(unsigned int, f);
  x += 0x7fffu + ((x >> 16) & 1u);     // RNE
  return (unsigned short)(x >> 16);
}

DEVI unsigned int cvtpk(float lo, float hi2) {  // low16=bf16(lo), high16=bf16(hi2), RNE
  unsigned int r;
  asm("v_cvt_pk_bf16_f32 %0, %1, %2" : "=v"(r) : "v"(lo), "v"(hi2));
  return r;
}

DEVI float exp2_raw(float x) {  // raw v_exp_f32 (2^x); x <= 0 here
  float r;
  asm("v_exp_f32 %0, %1" : "=v"(r) : "v"(x));
  return r;
}

DEVI int swz23(int r) {  // swap bits 2 and 3 (involution)
  const int d = ((r >> 2) ^ (r >> 3)) & 1;
  return r ^ (d << 2) ^ (d << 3);
}

DEVI bf16x8 mkfrag(unsigned a, unsigned b, unsigned c, unsigned d) {
  union { unsigned u[4]; bf16x8 v; } x;
  x.u[0] = a; x.u[1] = b; x.u[2] = c; x.u[3] = d;
  return x.v;
}

DEVI void gl2lds16(const void* g, const void* l) {
  __builtin_amdgcn_global_load_lds(
      (const __attribute__((address_space(1))) void*)g,
      (__attribute__((address_space(3))) void*)l, 16, 0, 0);
}

// ---------------------------------------------------------------- cast f32->bf16
__global__ __launch_bounds__(256) void k_cvt_bf16(const float* __restrict__ in,
                                                  unsigned short* __restrict__ out) {
  size_t i = ((size_t)blockIdx.x * 256 + threadIdx.x) * 8;
  float4 a = *(const float4*)(in + i);
  float4 b = *(const float4*)(in + i + 4);
  u16x8 o;
  o[0] = f2bf(a.x); o[1] = f2bf(a.y); o[2] = f2bf(a.z); o[3] = f2bf(a.w);
  o[4] = f2bf(b.x); o[5] = f2bf(b.y); o[6] = f2bf(b.z); o[7] = f2bf(b.w);
  *(u16x8*)(out + i) = o;
}

// ---------------------------------------------------------------- mask all-ones scan
__global__ __launch_bounds__(256) void k_mask_scan(const uint4* __restrict__ m,
                                                   unsigned int* __restrict__ flag) {
  const unsigned int ONE = 0x3f800000u;
  size_t i0 = ((size_t)blockIdx.x * 256 + threadIdx.x) * 8;   // 8 uint4 per thread
  bool ok = true;
#pragma unroll
  for (int i = 0; i < 8; ++i) {
    uint4 v = m[i0 + i];
    ok &= (v.x == ONE) & (v.y == ONE) & (v.z == ONE) & (v.w == ONE);
  }
  if (!ok) atomicAnd(flag, 0u);
}

// ------------------------------------------- transpose + cast: in f32[R][C] -> out bf16[C][R]
template <int R, int C>
__global__ __launch_bounds__(256) void k_transpose_cvt(const float* __restrict__ in,
                                                       unsigned short* __restrict__ out) {
  __shared__ unsigned short t[64][65];
  const int c0 = blockIdx.x * 64, r0 = blockIdx.y * 64;
  const int cc = threadIdx.x & 63, r4 = threadIdx.x >> 6;
#pragma unroll
  for (int i = 0; i < 16; ++i) {
    int rr = i * 4 + r4;
    t[rr][cc] = f2bf(in[(size_t)(r0 + rr) * C + c0 + cc]);
  }
  __syncthreads();
#pragma unroll
  for (int i = 0; i < 16; ++i) {
    int rr = i * 4 + r4;                       // output row (a column of in)
    out[(size_t)(c0 + rr) * R + r0 + cc] = t[cc][rr];
  }
}

// ---------------------------------------------- V[b,h,t,d] -> Vt[b,h,d,t]  (bf16)
__global__ __launch_bounds__(256) void k_transpose_v(const unsigned short* __restrict__ V,
                                                     unsigned short* __restrict__ Vt) {
  __shared__ unsigned short t[64][65];
  const int t0 = blockIdx.x * 64;
  const size_t bh = blockIdx.y;
  const unsigned short* src = V + (bh * T_ + t0) * 64;
  unsigned short* dst = Vt + bh * 64 * T_ + t0;
  const int cc = threadIdx.x & 63, r4 = threadIdx.x >> 6;
#pragma unroll
  for (int i = 0; i < 16; ++i) {
    int rr = i * 4 + r4;                       // t-local
    t[rr][cc] = src[(size_t)rr * 64 + cc];
  }
  __syncthreads();
#pragma unroll
  for (int i = 0; i < 16; ++i) {
    int rr = i * 4 + r4;                       // d
    dst[(size_t)rr * T_ + cc] = t[cc][rr];
  }
}

// ---------------------------------------------------------------- GEMM 256x128, BK=64
// (round-10 version -- best measured. 3-deep LDS ring + counted vmcnt, 16x16x32 MFMA:
// 16 independent accumulators give the ILP that the 32x32 shape lost, round-13 lesson.)
// group k reads buf k%3 while staging content k+2 into buf (k+2)%3; vmcnt(6) at
// group end keeps one content's loads in flight across barriers.
// 512 thr = 8 waves (4M x 2N), per-wave 64x64 out. grid % 8 == 0, XCD-swizzled.
template <int EPI, int NT>   // NT = N/128
__global__ __launch_bounds__(512, 2) void k_gemm8(
    const unsigned short* __restrict__ A, const unsigned short* __restrict__ Bt,
    const float* __restrict__ bias,
    unsigned short* __restrict__ qo, unsigned short* __restrict__ ko2,
    unsigned short* __restrict__ vo, float* __restrict__ fo) {
  __shared__ unsigned short As[3][256 * 64];   // 96 KiB
  __shared__ unsigned short Bs[3][128 * 64];   // 48 KiB
  const int tid = threadIdx.x, lane = tid & 63, w = tid >> 6;
  const int wm = w >> 1, wn = w & 1;           // 4 x 2 waves
  const int g = lane >> 4, c0 = lane & 15;

  const int flat = blockIdx.x;                 // nwg = 32*NT, % 8 == 0
  const int work = (flat & 7) * ((32 * NT) >> 3) + (flat >> 3);
  const int m0 = (work / NT) * 256, n0 = (work % NT) * 128;

  f32x4 acc[4][4] = {};

  // staging: slot s = tid + j*512 -> row s>>3, LDS chunk s&7 holds global chunk (s&7)^(row&7)
  const int rs = tid >> 3, chs = tid & 7;
  const int lwb = w * 512;                     // wave base (ushort) within a j-section

  auto stageK = [&](int buf, int kt) {
    const unsigned short* sa = A + (size_t)m0 * 1024 + kt * 64;
    const unsigned short* sb = Bt + (size_t)n0 * 1024 + kt * 64;
    unsigned short* da = &As[buf][0];
    unsigned short* db = &Bs[buf][0];
#pragma unroll
    for (int j = 0; j < 4; ++j) {
      const int row = rs + j * 64;
      const int ch = chs ^ (row & 7);
      gl2lds16(sa + (size_t)row * 1024 + ch * 8, da + j * 4096 + lwb);
    }
#pragma unroll
    for (int j = 0; j < 2; ++j) {
      const int row = rs + j * 64;
      const int ch = chs ^ (row & 7);
      gl2lds16(sb + (size_t)row * 1024 + ch * 8, db + j * 4096 + lwb);
    }
  };

  // prologue: contents 0,1 (12 loads); vmcnt(6) -> content 0 landed
  stageK(0, 0);
  stageK(1, 1);
  asm volatile("s_waitcnt vmcnt(6)" ::: "memory");
  __builtin_amdgcn_s_barrier();

  int cb = 0;
  for (int k = 0; k < 16; ++k) {
    bf16x8 af[4][2], bfv[4][2];
#pragma unroll
    for (int mf = 0; mf < 4; ++mf) {
      const int row = wm * 64 + mf * 16 + c0;
#pragma unroll
      for (int kk = 0; kk < 2; ++kk) {
        const int ch = (kk * 4 + g) ^ (row & 7);
        af[mf][kk] = *(const bf16x8*)&As[cb][row * 64 + ch * 8];
      }
    }
#pragma unroll
    for (int nf = 0; nf < 4; ++nf) {
      const int row = wn * 64 + nf * 16 + c0;
#pragma unroll
      for (int kk = 0; kk < 2; ++kk) {
        const int ch = (kk * 4 + g) ^ (row & 7);
        bfv[nf][kk] = *(const bf16x8*)&Bs[cb][row * 64 + ch * 8];
      }
    }
    if (k + 2 < 16) stageK((cb + 2) % 3, k + 2);
    __builtin_amdgcn_s_barrier();
    asm volatile("s_waitcnt lgkmcnt(0)" ::: "memory");
    __builtin_amdgcn_sched_barrier(0);
#pragma unroll
    for (int kk = 0; kk < 2; ++kk)
#pragma unroll
      for (int mf = 0; mf < 4; ++mf)
#pragma unroll
        for (int nf = 0; nf < 4; ++nf)
          acc[mf][nf] = __builtin_amdgcn_mfma_f32_16x16x32_bf16(af[mf][kk], bfv[nf][kk], acc[mf][nf], 0, 0, 0);
    if (k <= 13)      asm volatile("s_waitcnt vmcnt(6)" ::: "memory");
    else if (k == 14) asm volatile("s_waitcnt vmcnt(0)" ::: "memory");
    __builtin_amdgcn_s_barrier();
    cb = (cb == 2) ? 0 : cb + 1;
  }

#pragma unroll
  for (int mf = 0; mf < 4; ++mf) {
#pragma unroll
    for (int nf = 0; nf < 4; ++nf) {
      const int n = n0 + wn * 64 + nf * 16 + c0;
      const float bv = bias[n];
#pragma unroll
      for (int r = 0; r < 4; ++r) {
        const int m = m0 + wm * 64 + mf * 16 + g * 4 + r;
        float v = acc[mf][nf][r] + bv;
        if constexpr (EPI == 0) {
          const int sel = n >> 10, hd = n & 1023;
          const int h = hd >> 6, d = hd & 63;
          const int b = m >> 11, t = m & 2047;
          const size_t off = ((size_t)((b * 16 + h) * 2048 + t)) * 64 + d;
          if (sel == 0)       qo[off] = f2bf(v * 0.125f);   // q * DH^-0.5
          else if (sel == 1)  ko2[off] = f2bf(v);
          else                vo[off] = f2bf(v);
        } else {
          fo[(size_t)m * 1024 + n] = v;
        }
      }
    }
  }
}

// ---------------------------------------------------------------- flash attention
// (round-8/10 version -- best measured: 99.2-99.6 us across four runs)
// Swapped-operand: S^T = mfma(K,Q), lane owns q-row (q=lane&31); in-register softmax.
// K rows stored at LDS row swz23(t): lane's P register pairs map DIRECTLY onto
// PV B-fragment dwords (no cross-lane pack). PV as O^T = mfma(Vt,P).
// 4 waves x 32 q = 128 q / block; grid 1024 (XCD-swizzled); KVBLK=64 dbuf.
__global__ __launch_bounds__(256, 4) void k_attn(
    const unsigned short* __restrict__ Q, const unsigned short* __restrict__ Kg_,
    const unsigned short* __restrict__ Vt, const float* __restrict__ mask,
    const unsigned int* __restrict__ maskflag,
    unsigned short* __restrict__ ctx) {
  __shared__ unsigned short Ks[2][64 * 64];
  __shared__ unsigned short Vs[2][64 * 64];
  const int tid = threadIdx.x, lane = tid & 63, w = tid >> 6;
  const int q = lane & 31, hi = lane >> 5;

  // bijective XCD swizzle (1024 % 8 == 0): colocate the 16 q-blocks of one bh
  const int flat = blockIdx.x + 16 * blockIdx.y + 256 * blockIdx.z;
  const int work = (flat & 7) * 128 + (flat >> 3);
  const int qb = work & 15;
  const int bh_i = work >> 4;            // b*16 + h
  const int h = bh_i & 15, b = bh_i >> 4;
  const int t0 = qb * 128;
  const size_t bh = (size_t)bh_i;

  const unsigned short* Qg = Q + (bh * 2048 + t0 + w * 32 + q) * 64;
  const unsigned short* Kg = Kg_ + bh * 2048 * 64;
  const unsigned short* Vg = Vt + bh * 64 * 2048;
  const float* Mg = mask + (size_t)b * 2048 * 2048;
  const bool allones = (*maskflag != 0u);

  // Q as B-fragment of mfma(K,Q): lane: n=q, k = kd*16 + hi*8 + j
  bf16x8 qf[4];
#pragma unroll
  for (int kd = 0; kd < 4; ++kd)
    qf[kd] = *(const bf16x8*)(Qg + kd * 16 + hi * 8);

  f32x16 ot[2] = {};        // O^T acc: col=q, row d = dt*32 + (reg&3)+8*(reg>>2)+4*hi
  float mrun = -__builtin_inff(), lrun = 0.f;

  // staging: 128B rows, 8 chunks; LDS[r][ch] holds global chunk ch ^ (r&7).
  // K additionally row-permuted: LDS row r holds global K row swz23(r).
  const int s0 = tid, s1 = tid + 256;
  const int kr0 = s0 >> 3, kc0 = (s0 & 7) ^ (kr0 & 7);
  const int kr1 = s1 >> 3, kc1 = (s1 & 7) ^ (kr1 & 7);
  const int kp0 = swz23(kr0), kp1 = swz23(kr1);
  const int ldsb0 = w * 512, ldsb1 = w * 512 + 2048;

  auto stageKV = [&](int buf, int kt) {
    gl2lds16(Kg + (size_t)(kt * 64 + kp0) * 64 + kc0 * 8, &Ks[buf][ldsb0]);
    gl2lds16(Kg + (size_t)(kt * 64 + kp1) * 64 + kc1 * 8, &Ks[buf][ldsb1]);
    gl2lds16(Vg + (size_t)kr0 * 2048 + kt * 64 + kc0 * 8, &Vs[buf][ldsb0]);
    gl2lds16(Vg + (size_t)kr1 * 2048 + kt * 64 + kc1 * 8, &Vs[buf][ldsb1]);
  };

  stageKV(0, 0);
  __syncthreads();
  int cur = 0;
  const float MINF = -3.402823466e38f;
  const float L2E = 1.4426950408889634f;

  for (int kt = 0; kt < 32; ++kt) {
    if (kt + 1 < 32) stageKV(cur ^ 1, kt + 1);

    // S^T[m][q]: A = K rows from LDS (m = LDS row; global t2 = swz23(m)), B = Q frags
    f32x16 st[2] = {};
#pragma unroll
    for (int mt2 = 0; mt2 < 2; ++mt2) {
      __builtin_amdgcn_s_setprio(1);
#pragma unroll
      for (int kd = 0; kd < 4; ++kd) {
        const int row = mt2 * 32 + q;
        const int ch = (2 * kd + hi) ^ (row & 7);
        bf16x8 kf = *(const bf16x8*)&Ks[cur][row * 64 + ch * 8];
        st[mt2] = __builtin_amdgcn_mfma_f32_32x32x16_bf16(kf, qf[kd], st[mt2], 0, 0, 0);
      }
      __builtin_amdgcn_s_setprio(0);
    }

    // mask fallback: reg r holds m = (r&3)+4*hi+8*(r>>2); t2 = swz23(m)
    if (!allones) {
      const int qg = t0 + w * 32 + q;
#pragma unroll
      for (int mt2 = 0; mt2 < 2; ++mt2)
#pragma unroll
        for (int r = 0; r < 16; ++r) {
          const int kg = kt * 64 + mt2 * 32 +
                         (r & 3) + 4 * ((r >> 2) & 1) + 8 * hi + 16 * (r >> 3);
          const float mv = Mg[(size_t)qg * 2048 + kg];
          st[mt2][r] = st[mt2][r] * mv + (1.f - mv) * MINF;
        }
    }

    // ---- in-register online softmax ----
    float g4[8];
#pragma unroll
    for (int i = 0; i < 4; ++i) {
      g4[i]     = fmaxf(fmaxf(fmaxf(st[0][4 * i], st[0][4 * i + 1]), st[0][4 * i + 2]), st[0][4 * i + 3]);
      g4[i + 4] = fmaxf(fmaxf(fmaxf(st[1][4 * i], st[1][4 * i + 1]), st[1][4 * i + 2]), st[1][4 * i + 3]);
    }
    float r1 = fmaxf(fmaxf(g4[0], g4[1]), g4[2]);
    float r2 = fmaxf(fmaxf(g4[3], g4[4]), g4[5]);
    float r3 = fmaxf(fmaxf(g4[6], g4[7]), r1);
    float tmax = fmaxf(r2, r3);
    tmax = fmaxf(tmax, __shfl_xor(tmax, 32));
    const bool defer = (__all(tmax <= mrun + 8.f) != 0);   // T13 defer-max, THR=8
    float alpha = 1.f;
    if (!defer) {
      const float mnew = fmaxf(mrun, tmax);
      alpha = exp2_raw((mrun - mnew) * L2E);   // first iter: exp2(-inf)=0
      mrun = mnew;
    }
    const float mL2 = mrun * L2E;
#pragma unroll
    for (int mt2 = 0; mt2 < 2; ++mt2)
#pragma unroll
      for (int i = 0; i < 16; ++i)
        st[mt2][i] = exp2_raw(st[mt2][i] * L2E - mL2);
    float s8[8];
#pragma unroll
    for (int i = 0; i < 8; ++i)
      s8[i] = (st[0][i] + st[0][i + 8]) + (st[1][i] + st[1][i + 8]);
    float s4a = s8[0] + s8[4], s4b = s8[1] + s8[5];
    float s4c = s8[2] + s8[6], s4d = s8[3] + s8[7];
    float ps = (s4a + s4b) + (s4c + s4d);
    ps += __shfl_xor(ps, 32);
    lrun = lrun * alpha + ps;
    if (!defer) {
#pragma unroll
      for (int dt = 0; dt < 2; ++dt)
#pragma unroll
        for (int i = 0; i < 16; ++i) ot[dt][i] *= alpha;
    }

    // pack P to bf16 fragments -- pure in-lane thanks to the swz23 K-row layout
    bf16x8 pf[4];
#pragma unroll
    for (int mt2 = 0; mt2 < 2; ++mt2) {
      unsigned int pw[8];
#pragma unroll
      for (int i = 0; i < 8; ++i) pw[i] = cvtpk(st[mt2][2 * i], st[mt2][2 * i + 1]);
      pf[2 * mt2]     = mkfrag(pw[0], pw[1], pw[2], pw[3]);
      pf[2 * mt2 + 1] = mkfrag(pw[4], pw[5], pw[6], pw[7]);
    }

    // O^T += V^T P^T
#pragma unroll
    for (int dt = 0; dt < 2; ++dt) {
      __builtin_amdgcn_s_setprio(1);
#pragma unroll
      for (int kt2 = 0; kt2 < 4; ++kt2) {
        const int row = dt * 32 + q;
        const int ch = (2 * kt2 + hi) ^ (row & 7);
        bf16x8 vf = *(const bf16x8*)&Vs[cur][row * 64 + ch * 8];
        ot[dt] = __builtin_amdgcn_mfma_f32_32x32x16_bf16(vf, pf[kt2], ot[dt], 0, 0, 0);
      }
      __builtin_amdgcn_s_setprio(0);
    }

    __syncthreads();
    cur ^= 1;
  }

  // epilogue: lane owns q-row; d = dt*32 + rg*8 + hi*4 + {0..3} contiguous
  const int qg = t0 + w * 32 + q;
  const float rl = 1.f / lrun;
  unsigned short* cp = ctx + ((size_t)b * 2048 + qg) * 1024 + h * 64;
#pragma unroll
  for (int dt = 0; dt < 2; ++dt) {
#pragma unroll
    for (int rg = 0; rg < 4; ++rg) {
      const int d0 = dt * 32 + rg * 8 + hi * 4;
      ushort4 o;
      o.x = f2bf(ot[dt][rg * 4 + 0] * rl);
      o.y = f2bf(ot[dt][rg * 4 + 1] * rl);
      o.z = f2bf(ot[dt][rg * 4 + 2] * rl);
      o.w = f2bf(ot[dt][rg * 4 + 3] * rl);
      *(ushort4*)(cp + d0) = o;
    }
  }
}

// ----------------------------------------------------------------------------
extern "C" void kernel_launch(void* const* d_in, const int* in_sizes, int n_in,
                              void* d_out, int out_size, void* d_ws, size_t ws_size,
                              hipStream_t stream) {
  (void)in_sizes; (void)n_in; (void)out_size; (void)ws_size;
  const float* x    = (const float*)d_in[0];
  const float* Wqkv = (const float*)d_in[1];
  const float* bqkv = (const float*)d_in[2];
  const float* Wout = (const float*)d_in[3];
  const float* bout = (const float*)d_in[4];
  const float* mask = (const float*)d_in[5];
  float* out = (float*)d_out;
  char* ws = (char*)d_ws;

  const size_t SZ_BTD = (size_t)8192 * 1024 * 2;  // 16 MiB bf16 [B*T, D]
  unsigned short* xb  = (unsigned short*)(ws);
  unsigned short* Wqt = (unsigned short*)(ws + SZ_BTD);
  unsigned short* Wot = (unsigned short*)(ws + SZ_BTD + 6291456);
  unsigned short* Qb  = (unsigned short*)(ws + SZ_BTD + 8388608);
  unsigned short* Kb  = (unsigned short*)(ws + SZ_BTD + 8388608 + SZ_BTD);
  unsigned short* Vb  = (unsigned short*)(ws + SZ_BTD + 8388608 + 2 * SZ_BTD);
  unsigned short* Vtb = (unsigned short*)(ws + SZ_BTD + 8388608 + 3 * SZ_BTD);
  unsigned int* flag  = (unsigned int*)(ws + SZ_BTD + 8388608 + 4 * SZ_BTD);
  unsigned short* ctx = xb;  // reuse x_bf16 region (dead after gemm1)

  hipMemsetAsync(flag, 1, 4, stream);   // nonzero = "all ones so far"
  k_mask_scan<<<2048, 256, 0, stream>>>((const uint4*)mask, flag);
  k_cvt_bf16<<<4096, 256, 0, stream>>>(x, xb);
  k_transpose_cvt<1024, 3072><<<dim3(48, 16), 256, 0, stream>>>(Wqkv, Wqt);
  k_transpose_cvt<1024, 1024><<<dim3(16, 16), 256, 0, stream>>>(Wout, Wot);
  k_gemm8<0, 24><<<768, 512, 0, stream>>>(xb, Wqt, bqkv, Qb, Kb, Vb, nullptr);
  k_transpose_v<<<dim3(32, 64), 256, 0, stream>>>(Vb, Vtb);
  k_attn<<<dim3(16, 16, 4), 256, 0, stream>>>(Qb, Kb, Vtb, mask, flag, ctx);
  k_gemm8<1, 8><<<256, 512, 0, stream>>>(ctx, Wot, bout, nullptr, nullptr, nullptr, out);
}

// Round 15
// 215.544 us; speedup vs baseline: 1.0816x; 1.0394x over previous
//
#include <hip/hip_runtime.h>

typedef short bf16x8 __attribute__((ext_vector_type(8)));
typedef float f32x4 __attribute__((ext_vector_type(4)));
typedef float f32x16 __attribute__((ext_vector_type(16)));
typedef unsigned short u16x8 __attribute__((ext_vector_type(8)));

#define DEVI __device__ __forceinline__

// Problem constants: B=4, T=2048, D=1024, H=16, DH=64
static constexpr int T_ = 2048;

DEVI unsigned short f2bf(float f) {
  unsigned int x = __builtin_bit_cast(unsigned int, f);
  x += 0x7fffu + ((x >> 16) & 1u);     // RNE
  return (unsigned short)(x >> 16);
}

DEVI unsigned int cvtpk(float lo, float hi2) {  // low16=bf16(lo), high16=bf16(hi2), RNE
  unsigned int r;
  asm("v_cvt_pk_bf16_f32 %0, %1, %2" : "=v"(r) : "v"(lo), "v"(hi2));
  return r;
}

DEVI float exp2_raw(float x) {  // raw v_exp_f32 (2^x); x <= 0 here
  float r;
  asm("v_exp_f32 %0, %1" : "=v"(r) : "v"(x));
  return r;
}

DEVI int swz23(int r) {  // swap bits 2 and 3 (involution)
  const int d = ((r >> 2) ^ (r >> 3)) & 1;
  return r ^ (d << 2) ^ (d << 3);
}

DEVI bf16x8 mkfrag(unsigned a, unsigned b, unsigned c, unsigned d) {
  union { unsigned u[4]; bf16x8 v; } x;
  x.u[0] = a; x.u[1] = b; x.u[2] = c; x.u[3] = d;
  return x.v;
}

DEVI void gl2lds16(const void* g, const void* l) {
  __builtin_amdgcn_global_load_lds(
      (const __attribute__((address_space(1))) void*)g,
      (__attribute__((address_space(3))) void*)l, 16, 0, 0);
}

// ---------------------------------------------------------------- cast f32->bf16
__global__ __launch_bounds__(256) void k_cvt_bf16(const float* __restrict__ in,
                                                  unsigned short* __restrict__ out) {
  size_t i = ((size_t)blockIdx.x * 256 + threadIdx.x) * 8;
  float4 a = *(const float4*)(in + i);
  float4 b = *(const float4*)(in + i + 4);
  u16x8 o;
  o[0] = f2bf(a.x); o[1] = f2bf(a.y); o[2] = f2bf(a.z); o[3] = f2bf(a.w);
  o[4] = f2bf(b.x); o[5] = f2bf(b.y); o[6] = f2bf(b.z); o[7] = f2bf(b.w);
  *(u16x8*)(out + i) = o;
}

// ---------------------------------------------------------------- mask all-ones scan
__global__ __launch_bounds__(256) void k_mask_scan(const uint4* __restrict__ m,
                                                   unsigned int* __restrict__ flag) {
  const unsigned int ONE = 0x3f800000u;
  size_t i0 = ((size_t)blockIdx.x * 256 + threadIdx.x) * 8;   // 8 uint4 per thread
  bool ok = true;
#pragma unroll
  for (int i = 0; i < 8; ++i) {
    uint4 v = m[i0 + i];
    ok &= (v.x == ONE) & (v.y == ONE) & (v.z == ONE) & (v.w == ONE);
  }
  if (!ok) atomicAnd(flag, 0u);
}

// ------------------------------------------- transpose + cast: in f32[R][C] -> out bf16[C][R]
template <int R, int C>
__global__ __launch_bounds__(256) void k_transpose_cvt(const float* __restrict__ in,
                                                       unsigned short* __restrict__ out) {
  __shared__ unsigned short t[64][65];
  const int c0 = blockIdx.x * 64, r0 = blockIdx.y * 64;
  const int cc = threadIdx.x & 63, r4 = threadIdx.x >> 6;
#pragma unroll
  for (int i = 0; i < 16; ++i) {
    int rr = i * 4 + r4;
    t[rr][cc] = f2bf(in[(size_t)(r0 + rr) * C + c0 + cc]);
  }
  __syncthreads();
#pragma unroll
  for (int i = 0; i < 16; ++i) {
    int rr = i * 4 + r4;                       // output row (a column of in)
    out[(size_t)(c0 + rr) * R + r0 + cc] = t[cc][rr];
  }
}

// ---------------------------------------------------------------- GEMM 256x128, BK=64
// round-10 ring structure (3-deep LDS ring + counted vmcnt, 16x16x32 MFMA).
// NEW (EPI==0): V-blocks (n0>=2048) transpose their output tile through LDS in
// the epilogue and store coalesced directly to Vt[bh][d][t] -- the standalone
// k_transpose_v kernel is deleted. q/k blocks store as before (block-uniform sel).
// 512 thr = 8 waves (4M x 2N), per-wave 64x64 out. grid % 8 == 0, XCD-swizzled.
template <int EPI, int NT>   // NT = N/128
__global__ __launch_bounds__(512, 2) void k_gemm8(
    const unsigned short* __restrict__ A, const unsigned short* __restrict__ Bt,
    const float* __restrict__ bias,
    unsigned short* __restrict__ qo, unsigned short* __restrict__ ko2,
    unsigned short* __restrict__ vt, float* __restrict__ fo) {
  __shared__ unsigned short As[3][256 * 64];   // 96 KiB
  __shared__ unsigned short Bs[3][128 * 64];   // 48 KiB
  const int tid = threadIdx.x, lane = tid & 63, w = tid >> 6;
  const int wm = w >> 1, wn = w & 1;           // 4 x 2 waves
  const int g = lane >> 4, c0 = lane & 15;

  const int flat = blockIdx.x;                 // nwg = 32*NT, % 8 == 0
  const int work = (flat & 7) * ((32 * NT) >> 3) + (flat >> 3);
  const int m0 = (work / NT) * 256, n0 = (work % NT) * 128;

  f32x4 acc[4][4] = {};

  // staging: slot s = tid + j*512 -> row s>>3, LDS chunk s&7 holds global chunk (s&7)^(row&7)
  const int rs = tid >> 3, chs = tid & 7;
  const int lwb = w * 512;                     // wave base (ushort) within a j-section

  auto stageK = [&](int buf, int kt) {
    const unsigned short* sa = A + (size_t)m0 * 1024 + kt * 64;
    const unsigned short* sb = Bt + (size_t)n0 * 1024 + kt * 64;
    unsigned short* da = &As[buf][0];
    unsigned short* db = &Bs[buf][0];
#pragma unroll
    for (int j = 0; j < 4; ++j) {
      const int row = rs + j * 64;
      const int ch = chs ^ (row & 7);
      gl2lds16(sa + (size_t)row * 1024 + ch * 8, da + j * 4096 + lwb);
    }
#pragma unroll
    for (int j = 0; j < 2; ++j) {
      const int row = rs + j * 64;
      const int ch = chs ^ (row & 7);
      gl2lds16(sb + (size_t)row * 1024 + ch * 8, db + j * 4096 + lwb);
    }
  };

  // prologue: contents 0,1 (12 loads); vmcnt(6) -> content 0 landed
  stageK(0, 0);
  stageK(1, 1);
  asm volatile("s_waitcnt vmcnt(6)" ::: "memory");
  __builtin_amdgcn_s_barrier();

  int cb = 0;
  for (int k = 0; k < 16; ++k) {
    bf16x8 af[4][2], bfv[4][2];
#pragma unroll
    for (int mf = 0; mf < 4; ++mf) {
      const int row = wm * 64 + mf * 16 + c0;
#pragma unroll
      for (int kk = 0; kk < 2; ++kk) {
        const int ch = (kk * 4 + g) ^ (row & 7);
        af[mf][kk] = *(const bf16x8*)&As[cb][row * 64 + ch * 8];
      }
    }
#pragma unroll
    for (int nf = 0; nf < 4; ++nf) {
      const int row = wn * 64 + nf * 16 + c0;
#pragma unroll
      for (int kk = 0; kk < 2; ++kk) {
        const int ch = (kk * 4 + g) ^ (row & 7);
        bfv[nf][kk] = *(const bf16x8*)&Bs[cb][row * 64 + ch * 8];
      }
    }
    if (k + 2 < 16) stageK((cb + 2) % 3, k + 2);
    __builtin_amdgcn_s_barrier();
    asm volatile("s_waitcnt lgkmcnt(0)" ::: "memory");
    __builtin_amdgcn_sched_barrier(0);
#pragma unroll
    for (int kk = 0; kk < 2; ++kk)
#pragma unroll
      for (int mf = 0; mf < 4; ++mf)
#pragma unroll
        for (int nf = 0; nf < 4; ++nf)
          acc[mf][nf] = __builtin_amdgcn_mfma_f32_16x16x32_bf16(af[mf][kk], bfv[nf][kk], acc[mf][nf], 0, 0, 0);
    if (k <= 13)      asm volatile("s_waitcnt vmcnt(6)" ::: "memory");
    else if (k == 14) asm volatile("s_waitcnt vmcnt(0)" ::: "memory");
    __builtin_amdgcn_s_barrier();
    cb = (cb == 2) ? 0 : cb + 1;
  }

  if constexpr (EPI == 0) {
    if (n0 >= 2048) {
      // ---- V-block: transpose through LDS, store coalesced to vt[bh][d][t] ----
      // Vl logical [nl=128][ml=256] ushort; chunk-XOR swizzle: element ml of row
      // nl lives at physical ((ml>>3) ^ (nl&7))*8 + (ml&7). 64 KiB, aliases As
      // (dead after the final K-loop barrier above).
      unsigned short* Vl = &As[0][0];
#pragma unroll
      for (int mf = 0; mf < 4; ++mf) {
#pragma unroll
        for (int nf = 0; nf < 4; ++nf) {
          const int nl = wn * 64 + nf * 16 + c0;
          const float bv = bias[n0 + nl];
#pragma unroll
          for (int r = 0; r < 4; ++r) {
            const int ml = wm * 64 + mf * 16 + g * 4 + r;
            const int phys = (((ml >> 3) ^ (nl & 7)) << 3) + (ml & 7);
            Vl[nl * 256 + phys] = f2bf(acc[mf][nf][r] + bv);
          }
        }
      }
      __syncthreads();
      // store: thread -> row nl = tid>>2, t-chunk range [(tid&3)*8, +8)
      const int nl = tid >> 2;
      const int hd = (n0 - 2048) + nl;           // h changes at nl=64 within block
      const int h2 = hd >> 6, d2 = hd & 63;
      const int b2 = m0 >> 11, tba = m0 & 2047;  // b uniform: 256 | m0, 256 | 2048
      unsigned short* dst = vt + ((size_t)(b2 * 16 + h2) * 64 + d2) * 2048 + tba;
      const int cbase = (tid & 3) * 8;
#pragma unroll
      for (int j = 0; j < 8; ++j) {
        const int c = cbase + j;                 // logical t-chunk (8 ushort)
        const int pc = c ^ (nl & 7);             // physical chunk
        *(u16x8*)(dst + c * 8) = *(const u16x8*)&Vl[nl * 256 + pc * 8];
      }
    } else {
      // ---- q/k block (sel is block-uniform) ----
      const bool isq = (n0 < 1024);
#pragma unroll
      for (int mf = 0; mf < 4; ++mf) {
#pragma unroll
        for (int nf = 0; nf < 4; ++nf) {
          const int n = n0 + wn * 64 + nf * 16 + c0;
          const float bv = bias[n];
          const int hd = n & 1023;
          const int h = hd >> 6, d = hd & 63;
#pragma unroll
          for (int r = 0; r < 4; ++r) {
            const int m = m0 + wm * 64 + mf * 16 + g * 4 + r;
            const int b = m >> 11, t = m & 2047;
            const size_t off = ((size_t)((b * 16 + h) * 2048 + t)) * 64 + d;
            const float v = acc[mf][nf][r] + bv;
            if (isq) qo[off] = f2bf(v * 0.125f);   // q * DH^-0.5
            else     ko2[off] = f2bf(v);
          }
        }
      }
    }
  } else {
#pragma unroll
    for (int mf = 0; mf < 4; ++mf) {
#pragma unroll
      for (int nf = 0; nf < 4; ++nf) {
        const int n = n0 + wn * 64 + nf * 16 + c0;
        const float bv = bias[n];
#pragma unroll
        for (int r = 0; r < 4; ++r) {
          const int m = m0 + wm * 64 + mf * 16 + g * 4 + r;
          fo[(size_t)m * 1024 + n] = acc[mf][nf][r] + bv;
        }
      }
    }
  }
}

// ---------------------------------------------------------------- flash attention
// (round-8/10 version -- best measured: 99.0-99.6 us across five runs)
// Swapped-operand: S^T = mfma(K,Q), lane owns q-row (q=lane&31); in-register softmax.
// K rows stored at LDS row swz23(t): lane's P register pairs map DIRECTLY onto
// PV B-fragment dwords (no cross-lane pack). PV as O^T = mfma(Vt,P).
// 4 waves x 32 q = 128 q / block; grid 1024 (XCD-swizzled); KVBLK=64 dbuf.
__global__ __launch_bounds__(256, 4) void k_attn(
    const unsigned short* __restrict__ Q, const unsigned short* __restrict__ Kg_,
    const unsigned short* __restrict__ Vt, const float* __restrict__ mask,
    const unsigned int* __restrict__ maskflag,
    unsigned short* __restrict__ ctx) {
  __shared__ unsigned short Ks[2][64 * 64];
  __shared__ unsigned short Vs[2][64 * 64];
  const int tid = threadIdx.x, lane = tid & 63, w = tid >> 6;
  const int q = lane & 31, hi = lane >> 5;

  // bijective XCD swizzle (1024 % 8 == 0): colocate the 16 q-blocks of one bh
  const int flat = blockIdx.x + 16 * blockIdx.y + 256 * blockIdx.z;
  const int work = (flat & 7) * 128 + (flat >> 3);
  const int qb = work & 15;
  const int bh_i = work >> 4;            // b*16 + h
  const int h = bh_i & 15, b = bh_i >> 4;
  const int t0 = qb * 128;
  const size_t bh = (size_t)bh_i;

  const unsigned short* Qg = Q + (bh * 2048 + t0 + w * 32 + q) * 64;
  const unsigned short* Kg = Kg_ + bh * 2048 * 64;
  const unsigned short* Vg = Vt + bh * 64 * 2048;
  const float* Mg = mask + (size_t)b * 2048 * 2048;
  const bool allones = (*maskflag != 0u);

  // Q as B-fragment of mfma(K,Q): lane: n=q, k = kd*16 + hi*8 + j
  bf16x8 qf[4];
#pragma unroll
  for (int kd = 0; kd < 4; ++kd)
    qf[kd] = *(const bf16x8*)(Qg + kd * 16 + hi * 8);

  f32x16 ot[2] = {};        // O^T acc: col=q, row d = dt*32 + (reg&3)+8*(reg>>2)+4*hi
  float mrun = -__builtin_inff(), lrun = 0.f;

  // staging: 128B rows, 8 chunks; LDS[r][ch] holds global chunk ch ^ (r&7).
  // K additionally row-permuted: LDS row r holds global K row swz23(r).
  const int s0 = tid, s1 = tid + 256;
  const int kr0 = s0 >> 3, kc0 = (s0 & 7) ^ (kr0 & 7);
  const int kr1 = s1 >> 3, kc1 = (s1 & 7) ^ (kr1 & 7);
  const int kp0 = swz23(kr0), kp1 = swz23(kr1);
  const int ldsb0 = w * 512, ldsb1 = w * 512 + 2048;

  auto stageKV = [&](int buf, int kt) {
    gl2lds16(Kg + (size_t)(kt * 64 + kp0) * 64 + kc0 * 8, &Ks[buf][ldsb0]);
    gl2lds16(Kg + (size_t)(kt * 64 + kp1) * 64 + kc1 * 8, &Ks[buf][ldsb1]);
    gl2lds16(Vg + (size_t)kr0 * 2048 + kt * 64 + kc0 * 8, &Vs[buf][ldsb0]);
    gl2lds16(Vg + (size_t)kr1 * 2048 + kt * 64 + kc1 * 8, &Vs[buf][ldsb1]);
  };

  stageKV(0, 0);
  __syncthreads();
  int cur = 0;
  const float MINF = -3.402823466e38f;
  const float L2E = 1.4426950408889634f;

  for (int kt = 0; kt < 32; ++kt) {
    if (kt + 1 < 32) stageKV(cur ^ 1, kt + 1);

    // S^T[m][q]: A = K rows from LDS (m = LDS row; global t2 = swz23(m)), B = Q frags
    f32x16 st[2] = {};
#pragma unroll
    for (int mt2 = 0; mt2 < 2; ++mt2) {
      __builtin_amdgcn_s_setprio(1);
#pragma unroll
      for (int kd = 0; kd < 4; ++kd) {
        const int row = mt2 * 32 + q;
        const int ch = (2 * kd + hi) ^ (row & 7);
        bf16x8 kf = *(const bf16x8*)&Ks[cur][row * 64 + ch * 8];
        st[mt2] = __builtin_amdgcn_mfma_f32_32x32x16_bf16(kf, qf[kd], st[mt2], 0, 0, 0);
      }
      __builtin_amdgcn_s_setprio(0);
    }

    // mask fallback: reg r holds m = (r&3)+4*hi+8*(r>>2); t2 = swz23(m)
    if (!allones) {
      const int qg = t0 + w * 32 + q;
#pragma unroll
      for (int mt2 = 0; mt2 < 2; ++mt2)
#pragma unroll
        for (int r = 0; r < 16; ++r) {
          const int kg = kt * 64 + mt2 * 32 +
                         (r & 3) + 4 * ((r >> 2) & 1) + 8 * hi + 16 * (r >> 3);
          const float mv = Mg[(size_t)qg * 2048 + kg];
          st[mt2][r] = st[mt2][r] * mv + (1.f - mv) * MINF;
        }
    }

    // ---- in-register online softmax ----
    float g4[8];
#pragma unroll
    for (int i = 0; i < 4; ++i) {
      g4[i]     = fmaxf(fmaxf(fmaxf(st[0][4 * i], st[0][4 * i + 1]), st[0][4 * i + 2]), st[0][4 * i + 3]);
      g4[i + 4] = fmaxf(fmaxf(fmaxf(st[1][4 * i], st[1][4 * i + 1]), st[1][4 * i + 2]), st[1][4 * i + 3]);
    }
    float r1 = fmaxf(fmaxf(g4[0], g4[1]), g4[2]);
    float r2 = fmaxf(fmaxf(g4[3], g4[4]), g4[5]);
    float r3 = fmaxf(fmaxf(g4[6], g4[7]), r1);
    float tmax = fmaxf(r2, r3);
    tmax = fmaxf(tmax, __shfl_xor(tmax, 32));
    const bool defer = (__all(tmax <= mrun + 8.f) != 0);   // T13 defer-max, THR=8
    float alpha = 1.f;
    if (!defer) {
      const float mnew = fmaxf(mrun, tmax);
      alpha = exp2_raw((mrun - mnew) * L2E);   // first iter: exp2(-inf)=0
      mrun = mnew;
    }
    const float mL2 = mrun * L2E;
#pragma unroll
    for (int mt2 = 0; mt2 < 2; ++mt2)
#pragma unroll
      for (int i = 0; i < 16; ++i)
        st[mt2][i] = exp2_raw(st[mt2][i] * L2E - mL2);
    float s8[8];
#pragma unroll
    for (int i = 0; i < 8; ++i)
      s8[i] = (st[0][i] + st[0][i + 8]) + (st[1][i] + st[1][i + 8]);
    float s4a = s8[0] + s8[4], s4b = s8[1] + s8[5];
    float s4c = s8[2] + s8[6], s4d = s8[3] + s8[7];
    float ps = (s4a + s4b) + (s4c + s4d);
    ps += __shfl_xor(ps, 32);
    lrun = lrun * alpha + ps;
    if (!defer) {
#pragma unroll
      for (int dt = 0; dt < 2; ++dt)
#pragma unroll
        for (int i = 0; i < 16; ++i) ot[dt][i] *= alpha;
    }

    // pack P to bf16 fragments -- pure in-lane thanks to the swz23 K-row layout
    bf16x8 pf[4];
#pragma unroll
    for (int mt2 = 0; mt2 < 2; ++mt2) {
      unsigned int pw[8];
#pragma unroll
      for (int i = 0; i < 8; ++i) pw[i] = cvtpk(st[mt2][2 * i], st[mt2][2 * i + 1]);
      pf[2 * mt2]     = mkfrag(pw[0], pw[1], pw[2], pw[3]);
      pf[2 * mt2 + 1] = mkfrag(pw[4], pw[5], pw[6], pw[7]);
    }

    // O^T += V^T P^T
#pragma unroll
    for (int dt = 0; dt < 2; ++dt) {
      __builtin_amdgcn_s_setprio(1);
#pragma unroll
      for (int kt2 = 0; kt2 < 4; ++kt2) {
        const int row = dt * 32 + q;
        const int ch = (2 * kt2 + hi) ^ (row & 7);
        bf16x8 vf = *(const bf16x8*)&Vs[cur][row * 64 + ch * 8];
        ot[dt] = __builtin_amdgcn_mfma_f32_32x32x16_bf16(vf, pf[kt2], ot[dt], 0, 0, 0);
      }
      __builtin_amdgcn_s_setprio(0);
    }

    __syncthreads();
    cur ^= 1;
  }

  // epilogue: lane owns q-row; d = dt*32 + rg*8 + hi*4 + {0..3} contiguous
  const int qg = t0 + w * 32 + q;
  const float rl = 1.f / lrun;
  unsigned short* cp = ctx + ((size_t)b * 2048 + qg) * 1024 + h * 64;
#pragma unroll
  for (int dt = 0; dt < 2; ++dt) {
#pragma unroll
    for (int rg = 0; rg < 4; ++rg) {
      const int d0 = dt * 32 + rg * 8 + hi * 4;
      ushort4 o;
      o.x = f2bf(ot[dt][rg * 4 + 0] * rl);
      o.y = f2bf(ot[dt][rg * 4 + 1] * rl);
      o.z = f2bf(ot[dt][rg * 4 + 2] * rl);
      o.w = f2bf(ot[dt][rg * 4 + 3] * rl);
      *(ushort4*)(cp + d0) = o;
    }
  }
}

// ----------------------------------------------------------------------------
extern "C" void kernel_launch(void* const* d_in, const int* in_sizes, int n_in,
                              void* d_out, int out_size, void* d_ws, size_t ws_size,
                              hipStream_t stream) {
  (void)in_sizes; (void)n_in; (void)out_size; (void)ws_size;
  const float* x    = (const float*)d_in[0];
  const float* Wqkv = (const float*)d_in[1];
  const float* bqkv = (const float*)d_in[2];
  const float* Wout = (const float*)d_in[3];
  const float* bout = (const float*)d_in[4];
  const float* mask = (const float*)d_in[5];
  float* out = (float*)d_out;
  char* ws = (char*)d_ws;

  const size_t SZ_BTD = (size_t)8192 * 1024 * 2;  // 16 MiB bf16 [B*T, D]
  unsigned short* xb  = (unsigned short*)(ws);
  unsigned short* Wqt = (unsigned short*)(ws + SZ_BTD);
  unsigned short* Wot = (unsigned short*)(ws + SZ_BTD + 6291456);
  unsigned short* Qb  = (unsigned short*)(ws + SZ_BTD + 8388608);
  unsigned short* Kb  = (unsigned short*)(ws + SZ_BTD + 8388608 + SZ_BTD);
  unsigned short* Vtb = (unsigned short*)(ws + SZ_BTD + 8388608 + 2 * SZ_BTD);
  unsigned int* flag  = (unsigned int*)(ws + SZ_BTD + 8388608 + 3 * SZ_BTD);
  unsigned short* ctx = xb;  // reuse x_bf16 region (dead after gemm1)

  hipMemsetAsync(flag, 1, 4, stream);   // nonzero = "all ones so far"
  k_mask_scan<<<2048, 256, 0, stream>>>((const uint4*)mask, flag);
  k_cvt_bf16<<<4096, 256, 0, stream>>>(x, xb);
  k_transpose_cvt<1024, 3072><<<dim3(48, 16), 256, 0, stream>>>(Wqkv, Wqt);
  k_transpose_cvt<1024, 1024><<<dim3(16, 16), 256, 0, stream>>>(Wout, Wot);
  k_gemm8<0, 24><<<768, 512, 0, stream>>>(xb, Wqt, bqkv, Qb, Kb, Vtb, nullptr);
  k_attn<<<dim3(16, 16, 4), 256, 0, stream>>>(Qb, Kb, Vtb, mask, flag, ctx);
  k_gemm8<1, 8><<<256, 512, 0, stream>>>(ctx, Wot, bout, nullptr, nullptr, nullptr, out);
}